// Round 10
// baseline (370.607 us; speedup 1.0000x reference)
//
#include <hip/hip_runtime.h>
#include <hip/hip_bf16.h>
#include <stdint.h>

// MoE top-1: gate -> group by expert -> XCD-grouped dispatch tables ->
// grouped bf16-MFMA GEMMs. Round 10: B staged with float4 global loads
// (4 instr/thread/iter instead of 16 scalar dwords; 1KB contiguous per
// wave-instr) -> 3x fewer VMEM instructions, larger per-instr footprint
// for HBM miss-concurrency. ds_write_b64 with XOR swizzle ((n>>4)&3)<<3:
// write conflicts 8-way -> 2-way (free); frag reads keep uniform XOR,
// still lane-linear conflict-free.
#define N_TOK 4096
#define DIM   768
#define NE    8
#define HDIM  7680
#define ODIM  768
#define G1GRID 2816
#define G2GRID 1344

typedef __bf16 bf16x8 __attribute__((ext_vector_type(8)));
typedef float f32x4 __attribute__((ext_vector_type(4)));

__device__ __forceinline__ unsigned short f2bf(float f) {
    union { float f; unsigned u; } v; v.f = f;
    return (unsigned short)((v.u + 0x7fffu + ((v.u >> 16) & 1u)) >> 16);
}

__device__ __forceinline__ unsigned cvt_pk_bf16(float lo, float hi) {
    unsigned r;
    asm("v_cvt_pk_bf16_f32 %0, %1, %2" : "=v"(r) : "v"(lo), "v"(hi));
    return r;
}

__device__ __forceinline__ void gload_lds16(const unsigned short* g, unsigned short* l) {
    __builtin_amdgcn_global_load_lds(
        (const __attribute__((address_space(1))) unsigned int*)g,
        (__attribute__((address_space(3))) unsigned int*)l, 16, 0, 0);
}

// ---------------- gating & prep (validated rounds 1-9) ----------------
__global__ void moe_gating(const float* __restrict__ x, const float* __restrict__ Wg,
                           const float* __restrict__ bg, int* __restrict__ cnt,
                           int* __restrict__ top_e, int* __restrict__ rnk,
                           float* __restrict__ top_p) {
    const int wid  = threadIdx.x >> 6;
    const int lane = threadIdx.x & 63;
    const int t = blockIdx.x * 4 + wid;
    double p[NE];
#pragma unroll
    for (int j = 0; j < NE; ++j) p[j] = 0.0;
    const float* xr  = x  + (size_t)t * DIM + lane * 12;
    const float* wr0 = Wg + lane * 12 * NE;
#pragma unroll
    for (int i = 0; i < 12; ++i) {
        double xv = (double)xr[i];
#pragma unroll
        for (int j = 0; j < NE; ++j) p[j] += xv * (double)wr0[i * NE + j];
    }
#pragma unroll
    for (int off = 32; off >= 1; off >>= 1)
#pragma unroll
        for (int j = 0; j < NE; ++j) p[j] += __shfl_xor(p[j], off, 64);
    if (lane == 0) {
        double l[NE];
#pragma unroll
        for (int j = 0; j < NE; ++j) l[j] = p[j] + (double)bg[j];
        int be = 0; double bl = l[0];
#pragma unroll
        for (int j = 1; j < NE; ++j) if (l[j] > bl) { bl = l[j]; be = j; }
        double s = 0.0;
#pragma unroll
        for (int j = 0; j < NE; ++j) s += exp(l[j] - bl);
        int rk = atomicAdd(&cnt[be], 1);
        top_e[t] = be; rnk[t] = rk; top_p[t] = (float)(1.0 / s);
    }
}

__global__ void moe_init(int* cnt) { if (threadIdx.x < NE) cnt[threadIdx.x] = 0; }

__global__ void moe_scan(const int* __restrict__ cnt, int* __restrict__ offs,
                         int* __restrict__ mc, int* __restrict__ g1s,
                         int* __restrict__ g2s) {
    __shared__ int smc[NE];
    int tid = threadIdx.x;
    if (tid == 0) { int s = 0; for (int e = 0; e < NE; ++e) { offs[e] = s; s += cnt[e]; } }
    if (tid < NE) { smc[tid] = (cnt[tid] + 127) >> 7; mc[tid] = smc[tid]; }
    __syncthreads();
    if (tid < 8) {
        int s = 0;
        for (int j = 0; j < 60; ++j) { int p = tid + 8 * j; g1s[p] = s; s += smc[p / 60]; }
        int s2 = 0;
        for (int j = 0; j < 6; ++j)  { int p = tid + 8 * j; g2s[p] = s2; s2 += 4 * smc[p / 6]; }
    }
}

__global__ void moe_fill(const int* __restrict__ mc, const int* __restrict__ g1s,
                         const int* __restrict__ g2s, int* __restrict__ tbl1,
                         int* __restrict__ tbl2) {
    int gid = blockIdx.x * 256 + threadIdx.x;
    if (gid < G1GRID) {
        int c = gid & 7, slot = gid >> 3;
        int sel = c;
        for (int j = 0; j < 60; ++j) { int p = c + 8 * j; if (g1s[p] <= slot) sel = p; else break; }
        int e = sel / 60, n0 = sel % 60;
        int mt = slot - g1s[sel];
        tbl1[gid] = (mt < mc[e]) ? ((e << 14) | (mt << 8) | (n0 << 2)) : -1;
    } else if (gid < G1GRID + G2GRID) {
        int gg = gid - G1GRID;
        int c = gg & 7, slot = gg >> 3;
        int sel = c;
        for (int j = 0; j < 6; ++j) { int p = c + 8 * j; if (g2s[p] <= slot) sel = p; else break; }
        int e = sel / 6, n0 = sel % 6;
        int mem = slot - g2s[sel];
        int mcE = mc[e];
        int ks = mem / mcE, mt = mem - ks * mcE;
        tbl2[gg] = (mem < 4 * mcE) ? ((e << 14) | (mt << 8) | (n0 << 2) | ks) : -1;
    }
}

__global__ void moe_mkperm(const int* __restrict__ top_e, const int* __restrict__ rnk,
                           const float* __restrict__ top_p, const int* __restrict__ offs,
                           int* __restrict__ perm, float* __restrict__ gate_s) {
    int t = blockIdx.x * 256 + threadIdx.x;
    int e = top_e[t];
    int slot = offs[e] + rnk[t];
    perm[slot] = t;
    gate_s[slot] = top_p[t];
}

__global__ void moe_gather(const float* __restrict__ x, const int* __restrict__ perm,
                           unsigned short* __restrict__ Xg) {
    int slot = blockIdx.x;
    int t = perm[slot];
    const float* src = x + (size_t)t * DIM;
    unsigned short* dst = Xg + (size_t)slot * DIM;
    for (int i = threadIdx.x; i < DIM; i += 256) dst[i] = f2bf(src[i]);
}

__global__ void moe_initout(const int* __restrict__ top_e, const float* __restrict__ top_p,
                            const float* __restrict__ b2, float* __restrict__ out) {
    int t = blockIdx.x;
    int e = top_e[t];
    float gv = top_p[t];
    const float* b = b2 + (size_t)e * ODIM;
    float* o = out + (size_t)t * ODIM;
    for (int i = threadIdx.x; i < ODIM; i += 256) o[i] = gv * b[i];
}

// ---------------- grouped GEMM, float4-B unpinned depth-2 pipeline ----------------
// 128x128 tile, BK=32, 4 waves (2x2). A: triple-buffered global_load_lds
// issued 2 iters ahead. B: thread (n4=(tid&31)*4, kb=(tid>>5)*4) loads 4x
// float4 (k=kb..kb+3 rows, 4 consecutive n) 2 iters ahead -> 8 cvt_pk ->
// 4 ds_write_b64 at idx^((n>>4)&3)<<3 (2-way max). Frag reads lane-linear
// with the same uniform XOR per fragment: conflict-free.
template<int LAYER>
__global__ __launch_bounds__(256, 3) void moe_gemm(
    const unsigned short* __restrict__ A, const float* __restrict__ B,
    const float* __restrict__ bias, const int* __restrict__ cnt,
    const int* __restrict__ offs, const int* __restrict__ perm,
    const float* __restrict__ gate_s, const int* __restrict__ tbl,
    unsigned short* __restrict__ H, float* __restrict__ out) {

    constexpr int NT    = (LAYER == 1) ? HDIM : ODIM;
    constexpr int AST   = (LAYER == 1) ? DIM  : HDIM;
    constexpr int KFULL = (LAYER == 1) ? DIM  : HDIM;
    constexpr int KBLK  = (LAYER == 1) ? DIM  : HDIM / 4;
    constexpr int NITER = KBLK / 32;              // 24 / 60 (even, >=4)

    const int code = tbl[blockIdx.x];
    if (code < 0) return;
    const int e  = code >> 14;
    const int mt = (code >> 8) & 63;
    const int n0 = ((code >> 2) & 63) * 128;
    const int ks = code & 3;
    const int ne = cnt[e];
    const int base = offs[e];
    const int mlim = ne - mt * 128;
    const int kbase = ks * KBLK;

    __shared__ __align__(16) unsigned short As[3][4096];
    __shared__ __align__(16) unsigned short Bs[2][4096];

    const int tid = threadIdx.x;
    const int lane = tid & 63, w = tid >> 6;
    const int wr = w >> 1, wc = w & 1;
    const int g = lane >> 4, r = lane & 15;

    const int rl0 = 2 * w * 16 + r;
    const int rl1 = rl0 + 16;
    const int cr0 = rl0 < mlim ? rl0 : mlim - 1;
    const int cr1 = rl1 < mlim ? rl1 : mlim - 1;
    const unsigned short* aS0 = A + (size_t)(base + mt * 128 + cr0) * AST + kbase + g * 8;
    const unsigned short* aS1 = A + (size_t)(base + mt * 128 + cr1) * AST + kbase + g * 8;
    const int aD0 = (2 * w) * 512;
    const int aD1 = aD0 + 512;

    // B staging thread map: 4 consecutive n, 4 consecutive k per thread
    const int n4 = (tid & 31) * 4;
    const int kb = (tid >> 5) * 4;
    const float* bS = B + (size_t)e * KFULL * NT + (size_t)(kbase + kb) * NT + n0 + n4;
    // LDS ushort index of (n4, kb) before XOR; element (n,k) lives at
    // (n>>4)*512 + ((k>>3)&3)*128 + (n&15)*8 + (k&7), then ^ ((n>>4)&3)<<3.
    const int bwB  = (n4 >> 4) * 512 + ((kb >> 3) & 3) * 128 + (n4 & 15) * 8 + (kb & 7);
    const int bxor = ((n4 >> 4) & 3) << 3;

    f32x4 acc[4][4] = {};
    f32x4 bvA[4], bvB[4];

    unsigned short* A0 = &As[0][0];
    unsigned short* A1 = &As[1][0];
    unsigned short* A2 = &As[2][0];

#define LOADB(dst_, t_)                                                        \
    do { const float* bp_ = bS + (size_t)((t_) * 32) * NT;                     \
        _Pragma("unroll")                                                      \
        for (int i_ = 0; i_ < 4; ++i_)                                         \
            dst_[i_] = *(const f32x4*)(bp_ + (size_t)i_ * NT);                 \
    } while (0)

#define DMA_A(t_, abase_)                                                      \
    do { gload_lds16(aS0 + (t_) * 32, (abase_) + aD0);                         \
         gload_lds16(aS1 + (t_) * 32, (abase_) + aD1); } while (0)

// Repack k-major: for each of 4 n, pack k=kb..kb+3 into one 8B write.
#define COMMITB(src_, buf_)                                                    \
    do { _Pragma("unroll")                                                     \
        for (int j_ = 0; j_ < 4; ++j_) {                                       \
            uint2 q_;                                                          \
            q_.x = cvt_pk_bf16(src_[0][j_], src_[1][j_]);                      \
            q_.y = cvt_pk_bf16(src_[2][j_], src_[3][j_]);                      \
            *(uint2*)&Bs[buf_][(bwB + j_ * 8) ^ bxor] = q_;                     \
        }                                                                      \
    } while (0)

#define PHASE_END                                                              \
    do { asm volatile("s_waitcnt lgkmcnt(0)" ::: "memory");                    \
         __builtin_amdgcn_s_barrier();                                         \
         __builtin_amdgcn_sched_barrier(0); } while (0)

// MODE 2: steady. MODE 1: t==NITER-2 (no new loads). MODE 0: last, no barrier.
// In-order vmcnt retirement: using bv(t+1) in COMMITB retires DMA(t+1) too.
#define BODY(t_, cur_, ARD_, ADMA_, LDst_, CMsrc_, MODE_)                      \
    do {                                                                       \
        bf16x8 af_[4], bf_[4];                                                 \
        _Pragma("unroll")                                                      \
        for (int m_ = 0; m_ < 4; ++m_)                                         \
            af_[m_] = *(const bf16x8*)((ARD_) + (wr * 4 + m_) * 512 + lane * 8); \
        _Pragma("unroll")                                                      \
        for (int n_ = 0; n_ < 4; ++n_)                                         \
            bf_[n_] = *(const bf16x8*)&Bs[cur_][                               \
                (((wc * 4 + n_) * 512) + lane * 8) ^ ((n_ & 3) << 3)];         \
        if (MODE_ == 2) DMA_A((t_) + 2, ADMA_);                                \
        if (MODE_ == 2) LOADB(LDst_, (t_) + 2);                                \
        _Pragma("unroll")                                                      \
        for (int n_ = 0; n_ < 4; ++n_)                                         \
            _Pragma("unroll")                                                  \
            for (int m_ = 0; m_ < 4; ++m_)                                     \
                acc[m_][n_] = __builtin_amdgcn_mfma_f32_16x16x32_bf16(         \
                    af_[m_], bf_[n_], acc[m_][n_], 0, 0, 0);                   \
        if (MODE_ >= 1) { COMMITB(CMsrc_, (cur_) ^ 1); PHASE_END; }            \
    } while (0)

    // prologue: DMA(0), B(0), DMA(1), B(1); commit B(0) (auto vmcnt retires DMA(0))
    DMA_A(0, A0);
    LOADB(bvA, 0);
    DMA_A(1, A1);
    LOADB(bvB, 1);
    COMMITB(bvA, 0);
    PHASE_END;

    // invariant at loop head: A0=buf(t%3), A1=buf(t+1), A2=buf(t+2)
#pragma unroll 1
    for (int t = 0; t + 4 <= NITER; t += 2) {
        BODY(t,     0, A0, A2, bvA, bvB, 2);
        BODY(t + 1, 1, A1, A0, bvB, bvA, 2);
        unsigned short* tr_ = A2; A2 = A1; A1 = A0; A0 = tr_;
    }
    BODY(NITER - 2, 0, A0, A2, bvA, bvB, 1);
    BODY(NITER - 1, 1, A1, A2, bvB, bvA, 0);

#undef BODY
#undef PHASE_END
#undef COMMITB
#undef DMA_A
#undef LOADB

    // epilogue: C/D layout col = lane&15 (=r), row = 4*(lane>>4) (=4g) + reg
#pragma unroll
    for (int m = 0; m < 4; ++m) {
#pragma unroll
        for (int j = 0; j < 4; ++j) {
            int lrow = mt * 128 + wr * 64 + m * 16 + g * 4 + j;
            if (lrow < ne) {
                int slot = base + lrow;
#pragma unroll
                for (int n = 0; n < 4; ++n) {
                    int col = n0 + wc * 64 + n * 16 + r;
                    if constexpr (LAYER == 1) {
                        float v = acc[m][n][j] + bias[(size_t)e * NT + col];
                        v = fmaxf(v, 0.0f);
                        H[(size_t)slot * HDIM + col] = f2bf(v);
                    } else {
                        atomicAdd(&out[(size_t)perm[slot] * ODIM + col],
                                  gate_s[slot] * acc[m][n][j]);
                    }
                }
            }
        }
    }
}

// ---------------- launch ----------------
extern "C" void kernel_launch(void* const* d_in, const int* in_sizes, int n_in,
                              void* d_out, int out_size, void* d_ws, size_t ws_size,
                              hipStream_t stream) {
    const float* x  = (const float*)d_in[0];
    const float* Wg = (const float*)d_in[1];
    const float* bg = (const float*)d_in[2];
    const float* W1 = (const float*)d_in[3];
    const float* b1 = (const float*)d_in[4];
    const float* W2 = (const float*)d_in[5];
    const float* b2 = (const float*)d_in[6];
    float* out = (float*)d_out;

    char* ws = (char*)d_ws;
    int*   cnt    = (int*)(ws + 0);
    int*   offs   = (int*)(ws + 64);
    int*   mc     = (int*)(ws + 128);
    int*   g1s    = (int*)(ws + 256);
    int*   g2s    = (int*)(ws + 2304);
    int*   tbl1   = (int*)(ws + 3072);
    int*   tbl2   = (int*)(ws + 14336);
    int*   top_e  = (int*)(ws + 19712);
    int*   rnk    = (int*)(ws + 19712 + 16384);
    float* top_p  = (float*)(ws + 19712 + 2 * 16384);
    int*   perm   = (int*)(ws + 19712 + 3 * 16384);
    float* gate_s = (float*)(ws + 19712 + 4 * 16384);
    unsigned short* Xg = (unsigned short*)(ws + 101632);
    unsigned short* H  = (unsigned short*)(ws + 101632 + (size_t)N_TOK * DIM * 2);
    // total ws: ~69.3 MB

    moe_init<<<1, 64, 0, stream>>>(cnt);
    moe_gating<<<N_TOK / 4, 256, 0, stream>>>(x, Wg, bg, cnt, top_e, rnk, top_p);
    moe_scan<<<1, 64, 0, stream>>>(cnt, offs, mc, g1s, g2s);
    moe_fill<<<(G1GRID + G2GRID + 255) / 256, 256, 0, stream>>>(mc, g1s, g2s, tbl1, tbl2);
    moe_mkperm<<<N_TOK / 256, 256, 0, stream>>>(top_e, rnk, top_p, offs, perm, gate_s);
    moe_gather<<<N_TOK, 256, 0, stream>>>(x, perm, Xg);
    moe_initout<<<N_TOK, 256, 0, stream>>>(top_e, top_p, b2, out);

    moe_gemm<1><<<G1GRID, 256, 0, stream>>>(Xg, W1, b1, cnt, offs, perm, gate_s, tbl1, H, out);
    moe_gemm<2><<<G2GRID, 256, 0, stream>>>(H, W2, b2, cnt, offs, perm, gate_s, tbl2, H, out);
}

// Round 11
// 363.971 us; speedup vs baseline: 1.0182x; 1.0182x over previous
//
#include <hip/hip_runtime.h>
#include <hip/hip_bf16.h>
#include <stdint.h>

// MoE top-1: gate -> group by expert -> XCD-grouped dispatch tables ->
// grouped bf16-MFMA GEMMs. Round 11: EPILOGUE overhaul. K-loop = r9's
// (unpinned depth-2, 0 bank conflicts, validated). GEMM1: C through
// wave-private LDS -> 8x dwordx4 coalesced H stores (was 64 scalar u16).
// GEMM2: NO atomics -- f32 partials to part[ks][slot][col] via LDS
// transpose + separate reduce kernel folding bias+gate (was 64 atomicAdd).
#define N_TOK 4096
#define DIM   768
#define NE    8
#define HDIM  7680
#define ODIM  768
#define G1GRID 2816
#define G2GRID 1344

typedef __bf16 bf16x8 __attribute__((ext_vector_type(8)));
typedef float f32x4 __attribute__((ext_vector_type(4)));

__device__ __forceinline__ unsigned short f2bf(float f) {
    union { float f; unsigned u; } v; v.f = f;
    return (unsigned short)((v.u + 0x7fffu + ((v.u >> 16) & 1u)) >> 16);
}

__device__ __forceinline__ unsigned cvt_pk_bf16(float lo, float hi) {
    unsigned r;
    asm("v_cvt_pk_bf16_f32 %0, %1, %2" : "=v"(r) : "v"(lo), "v"(hi));
    return r;
}

__device__ __forceinline__ void gload_lds16(const unsigned short* g, unsigned short* l) {
    __builtin_amdgcn_global_load_lds(
        (const __attribute__((address_space(1))) unsigned int*)g,
        (__attribute__((address_space(3))) unsigned int*)l, 16, 0, 0);
}

// ---------------- gating & prep (validated rounds 1-10) ----------------
__global__ void moe_gating(const float* __restrict__ x, const float* __restrict__ Wg,
                           const float* __restrict__ bg, int* __restrict__ cnt,
                           int* __restrict__ top_e, int* __restrict__ rnk,
                           float* __restrict__ top_p) {
    const int wid  = threadIdx.x >> 6;
    const int lane = threadIdx.x & 63;
    const int t = blockIdx.x * 4 + wid;
    double p[NE];
#pragma unroll
    for (int j = 0; j < NE; ++j) p[j] = 0.0;
    const float* xr  = x  + (size_t)t * DIM + lane * 12;
    const float* wr0 = Wg + lane * 12 * NE;
#pragma unroll
    for (int i = 0; i < 12; ++i) {
        double xv = (double)xr[i];
#pragma unroll
        for (int j = 0; j < NE; ++j) p[j] += xv * (double)wr0[i * NE + j];
    }
#pragma unroll
    for (int off = 32; off >= 1; off >>= 1)
#pragma unroll
        for (int j = 0; j < NE; ++j) p[j] += __shfl_xor(p[j], off, 64);
    if (lane == 0) {
        double l[NE];
#pragma unroll
        for (int j = 0; j < NE; ++j) l[j] = p[j] + (double)bg[j];
        int be = 0; double bl = l[0];
#pragma unroll
        for (int j = 1; j < NE; ++j) if (l[j] > bl) { bl = l[j]; be = j; }
        double s = 0.0;
#pragma unroll
        for (int j = 0; j < NE; ++j) s += exp(l[j] - bl);
        int rk = atomicAdd(&cnt[be], 1);
        top_e[t] = be; rnk[t] = rk; top_p[t] = (float)(1.0 / s);
    }
}

__global__ void moe_init(int* cnt) { if (threadIdx.x < NE) cnt[threadIdx.x] = 0; }

__global__ void moe_scan(const int* __restrict__ cnt, int* __restrict__ offs,
                         int* __restrict__ mc, int* __restrict__ g1s,
                         int* __restrict__ g2s) {
    __shared__ int smc[NE];
    int tid = threadIdx.x;
    if (tid == 0) { int s = 0; for (int e = 0; e < NE; ++e) { offs[e] = s; s += cnt[e]; } }
    if (tid < NE) { smc[tid] = (cnt[tid] + 127) >> 7; mc[tid] = smc[tid]; }
    __syncthreads();
    if (tid < 8) {
        int s = 0;
        for (int j = 0; j < 60; ++j) { int p = tid + 8 * j; g1s[p] = s; s += smc[p / 60]; }
        int s2 = 0;
        for (int j = 0; j < 6; ++j)  { int p = tid + 8 * j; g2s[p] = s2; s2 += 4 * smc[p / 6]; }
    }
}

__global__ void moe_fill(const int* __restrict__ mc, const int* __restrict__ g1s,
                         const int* __restrict__ g2s, int* __restrict__ tbl1,
                         int* __restrict__ tbl2) {
    int gid = blockIdx.x * 256 + threadIdx.x;
    if (gid < G1GRID) {
        int c = gid & 7, slot = gid >> 3;
        int sel = c;
        for (int j = 0; j < 60; ++j) { int p = c + 8 * j; if (g1s[p] <= slot) sel = p; else break; }
        int e = sel / 60, n0 = sel % 60;
        int mt = slot - g1s[sel];
        tbl1[gid] = (mt < mc[e]) ? ((e << 14) | (mt << 8) | (n0 << 2)) : -1;
    } else if (gid < G1GRID + G2GRID) {
        int gg = gid - G1GRID;
        int c = gg & 7, slot = gg >> 3;
        int sel = c;
        for (int j = 0; j < 6; ++j) { int p = c + 8 * j; if (g2s[p] <= slot) sel = p; else break; }
        int e = sel / 6, n0 = sel % 6;
        int mem = slot - g2s[sel];
        int mcE = mc[e];
        int ks = mem / mcE, mt = mem - ks * mcE;
        tbl2[gg] = (mem < 4 * mcE) ? ((e << 14) | (mt << 8) | (n0 << 2) | ks) : -1;
    }
}

__global__ void moe_mkperm(const int* __restrict__ top_e, const int* __restrict__ rnk,
                           const float* __restrict__ top_p, const int* __restrict__ offs,
                           int* __restrict__ perm, float* __restrict__ gate_s) {
    int t = blockIdx.x * 256 + threadIdx.x;
    int e = top_e[t];
    int slot = offs[e] + rnk[t];
    perm[slot] = t;
    gate_s[slot] = top_p[t];
}

__global__ void moe_gather(const float* __restrict__ x, const int* __restrict__ perm,
                           unsigned short* __restrict__ Xg) {
    int slot = blockIdx.x;
    int t = perm[slot];
    const float* src = x + (size_t)t * DIM;
    unsigned short* dst = Xg + (size_t)slot * DIM;
    for (int i = threadIdx.x; i < DIM; i += 256) dst[i] = f2bf(src[i]);
}

// out[t] = gate * (sum_ks part[ks][slot] + b2[e])
__global__ void moe_reduce(const float* __restrict__ part, const int* __restrict__ perm,
                           const float* __restrict__ gate_s, const int* __restrict__ top_e,
                           const float* __restrict__ b2, float* __restrict__ out) {
    int slot = blockIdx.x;
    int t = perm[slot];
    int e = top_e[t];
    float gv = gate_s[slot];
    int c = threadIdx.x * 4;                       // 192 threads x 4 cols
    f32x4 s = *(const f32x4*)&b2[(size_t)e * ODIM + c];
#pragma unroll
    for (int ks = 0; ks < 4; ++ks)
        s += *(const f32x4*)&part[((size_t)ks * N_TOK + slot) * ODIM + c];
    s *= gv;
    *(f32x4*)&out[(size_t)t * ODIM + c] = s;
}

// ---------------- grouped GEMM, unpinned depth-2 pipeline ----------------
// K-loop identical to round 9 (0 bank conflicts). Epilogue: C staged through
// wave-private LDS (chunk-XOR swizzled), written back coalesced (dwordx4).
template<int LAYER>
__global__ __launch_bounds__(256, 3) void moe_gemm(
    const unsigned short* __restrict__ A, const float* __restrict__ B,
    const float* __restrict__ bias, const int* __restrict__ cnt,
    const int* __restrict__ offs, const int* __restrict__ tbl,
    unsigned short* __restrict__ H, float* __restrict__ part) {

    constexpr int NT    = (LAYER == 1) ? HDIM : ODIM;
    constexpr int AST   = (LAYER == 1) ? DIM  : HDIM;
    constexpr int KFULL = (LAYER == 1) ? DIM  : HDIM;
    constexpr int KBLK  = (LAYER == 1) ? DIM  : HDIM / 4;
    constexpr int NITER = KBLK / 32;              // 24 / 60 (even, >=4)

    const int code = tbl[blockIdx.x];
    if (code < 0) return;
    const int e  = code >> 14;
    const int mt = (code >> 8) & 63;
    const int n0 = ((code >> 2) & 63) * 128;
    const int ks = code & 3;
    const int ne = cnt[e];
    const int base = offs[e];
    const int mlim = ne - mt * 128;
    const int kbase = ks * KBLK;

    __shared__ __align__(16) unsigned short LDSu[5][4096];   // A triple + B double

    const int tid = threadIdx.x;
    const int lane = tid & 63, w = tid >> 6;
    const int wr = w >> 1, wc = w & 1;
    const int g = lane >> 4, r = lane & 15;

    const int rl0 = 2 * w * 16 + r;
    const int rl1 = rl0 + 16;
    const int cr0 = rl0 < mlim ? rl0 : mlim - 1;
    const int cr1 = rl1 < mlim ? rl1 : mlim - 1;
    const unsigned short* aS0 = A + (size_t)(base + mt * 128 + cr0) * AST + kbase + g * 8;
    const unsigned short* aS1 = A + (size_t)(base + mt * 128 + cr1) * AST + kbase + g * 8;
    const int aD0 = (2 * w) * 512;
    const int aD1 = aD0 + 512;

    const int bn = tid & 127;
    const int kh = tid >> 7;
    const float* bS = B + (size_t)e * KFULL * NT + (size_t)(kbase + kh * 16) * NT + n0 + bn;
    const int bD = (bn >> 4) * 512 + (kh * 2) * 128 + (bn & 15) * 8;

    f32x4 acc[4][4] = {};
    float bvA[16], bvB[16];

    unsigned short* A0 = &LDSu[0][0];
    unsigned short* A1 = &LDSu[1][0];
    unsigned short* A2 = &LDSu[2][0];
    unsigned short* Bsb = &LDSu[3][0];

#define LOADB(dst_, t_)                                                        \
    do { const float* bp_ = bS + (size_t)((t_) * 32) * NT;                     \
        _Pragma("unroll")                                                      \
        for (int i_ = 0; i_ < 16; ++i_) dst_[i_] = bp_[(size_t)i_ * NT];       \
    } while (0)

#define DMA_A(t_, abase_)                                                      \
    do { gload_lds16(aS0 + (t_) * 32, (abase_) + aD0);                         \
         gload_lds16(aS1 + (t_) * 32, (abase_) + aD1); } while (0)

#define COMMITB(src_, buf_)                                                    \
    do { uint4 q0_, q1_;                                                       \
        q0_.x = cvt_pk_bf16(src_[0],  src_[1]);  q0_.y = cvt_pk_bf16(src_[2],  src_[3]);  \
        q0_.z = cvt_pk_bf16(src_[4],  src_[5]);  q0_.w = cvt_pk_bf16(src_[6],  src_[7]);  \
        q1_.x = cvt_pk_bf16(src_[8],  src_[9]);  q1_.y = cvt_pk_bf16(src_[10], src_[11]); \
        q1_.z = cvt_pk_bf16(src_[12], src_[13]); q1_.w = cvt_pk_bf16(src_[14], src_[15]); \
        *(uint4*)(Bsb + (buf_) * 4096 + bD)       = q0_;                       \
        *(uint4*)(Bsb + (buf_) * 4096 + bD + 128) = q1_;                       \
    } while (0)

#define PHASE_END                                                              \
    do { asm volatile("s_waitcnt lgkmcnt(0)" ::: "memory");                    \
         __builtin_amdgcn_s_barrier();                                         \
         __builtin_amdgcn_sched_barrier(0); } while (0)

#define BODY(t_, cur_, ARD_, ADMA_, LDst_, CMsrc_, MODE_)                      \
    do {                                                                       \
        bf16x8 af_[4], bf_[4];                                                 \
        _Pragma("unroll")                                                      \
        for (int m_ = 0; m_ < 4; ++m_)                                         \
            af_[m_] = *(const bf16x8*)((ARD_) + (wr * 4 + m_) * 512 + lane * 8); \
        _Pragma("unroll")                                                      \
        for (int n_ = 0; n_ < 4; ++n_)                                         \
            bf_[n_] = *(const bf16x8*)(Bsb + (cur_) * 4096 +                   \
                                       (wc * 4 + n_) * 512 + lane * 8);        \
        if (MODE_ == 2) DMA_A((t_) + 2, ADMA_);                                \
        if (MODE_ == 2) LOADB(LDst_, (t_) + 2);                                \
        _Pragma("unroll")                                                      \
        for (int n_ = 0; n_ < 4; ++n_)                                         \
            _Pragma("unroll")                                                  \
            for (int m_ = 0; m_ < 4; ++m_)                                     \
                acc[m_][n_] = __builtin_amdgcn_mfma_f32_16x16x32_bf16(         \
                    af_[m_], bf_[n_], acc[m_][n_], 0, 0, 0);                   \
        if (MODE_ >= 1) { COMMITB(CMsrc_, (cur_) ^ 1); PHASE_END; }            \
    } while (0)

    DMA_A(0, A0);
    LOADB(bvA, 0);
    DMA_A(1, A1);
    LOADB(bvB, 1);
    COMMITB(bvA, 0);
    PHASE_END;

#pragma unroll 1
    for (int t = 0; t + 4 <= NITER; t += 2) {
        BODY(t,     0, A0, A2, bvA, bvB, 2);
        BODY(t + 1, 1, A1, A0, bvB, bvA, 2);
        unsigned short* tr_ = A2; A2 = A1; A1 = A0; A0 = tr_;
    }
    BODY(NITER - 2, 0, A0, A2, bvA, bvB, 1);
    BODY(NITER - 1, 1, A1, A2, bvB, bvA, 0);

#undef BODY
#undef PHASE_END
#undef COMMITB
#undef DMA_A
#undef LOADB

    // ---------------- epilogue: LDS-staged coalesced C write ----------------
    // acc[m][n][j] -> (row = wr*64 + m*16 + g*4 + j, col = wc*64 + n*16 + r).
    // Wave-private 10KB LDS region; chunk-XOR swizzle (^row&7 on 16B-chunk
    // index) makes readback b128 reads conflict-free.
    __builtin_amdgcn_s_barrier();            // all waves done with K-loop LDS
    unsigned short* cw = &LDSu[0][0] + w * 5120;

    if constexpr (LAYER == 1) {
        float bfv[4];
#pragma unroll
        for (int n = 0; n < 4; ++n)
            bfv[n] = bias[(size_t)e * NT + n0 + wc * 64 + n * 16 + r];
#pragma unroll
        for (int m = 0; m < 4; ++m)
#pragma unroll
            for (int n = 0; n < 4; ++n)
#pragma unroll
                for (int j = 0; j < 4; ++j) {
                    int rowl = m * 16 + g * 4 + j;
                    int coll = n * 16 + r;
                    float v = fmaxf(acc[m][n][j] + bfv[n], 0.0f);
                    cw[rowl * 64 + (coll ^ ((rowl & 7) << 3))] = f2bf(v);
                }
        asm volatile("s_waitcnt lgkmcnt(0)" ::: "memory");
#pragma unroll
        for (int i = 0; i < 8; ++i) {
            int rowl = i * 8 + (lane >> 3);
            int ch = ((lane & 7) ^ (rowl & 7)) * 8;      // swizzled 16B chunk
            uint4 q = *(const uint4*)&cw[rowl * 64 + ch];
            int gcol = ((lane & 7) * 8);                  // logical col
            int lrow = mt * 128 + wr * 64 + rowl;
            if (lrow < ne)
                *(uint4*)&H[(size_t)(base + lrow) * HDIM + n0 + wc * 64 + gcol] = q;
        }
    } else {
        float* cwf = (float*)cw;                          // 2 passes of 32x64 f32
#pragma unroll
        for (int h = 0; h < 2; ++h) {
#pragma unroll
            for (int mm = 0; mm < 2; ++mm)
#pragma unroll
                for (int n = 0; n < 4; ++n)
#pragma unroll
                    for (int j = 0; j < 4; ++j) {
                        int rowl = mm * 16 + g * 4 + j;
                        int coll = n * 16 + r;
                        cwf[rowl * 64 + (coll ^ ((rowl & 7) << 2))] = acc[h * 2 + mm][n][j];
                    }
            asm volatile("s_waitcnt lgkmcnt(0)" ::: "memory");
#pragma unroll
            for (int i = 0; i < 8; ++i) {
                int rowl = (i >> 1) * 8 + (lane >> 3);
                int ci = (i & 1) * 8 + (lane & 7);        // logical 16B chunk
                int cs = ((i & 1) * 8 + ((lane & 7) ^ (rowl & 7))) * 4;
                f32x4 q = *(const f32x4*)&cwf[rowl * 64 + cs];
                int lrow = mt * 128 + wr * 64 + h * 32 + rowl;
                if (lrow < ne)
                    *(f32x4*)&part[((size_t)ks * N_TOK + (base + lrow)) * ODIM
                                   + n0 + wc * 64 + ci * 4] = q;
            }
            asm volatile("s_waitcnt lgkmcnt(0)" ::: "memory");
        }
    }
}

// ---------------- launch ----------------
extern "C" void kernel_launch(void* const* d_in, const int* in_sizes, int n_in,
                              void* d_out, int out_size, void* d_ws, size_t ws_size,
                              hipStream_t stream) {
    const float* x  = (const float*)d_in[0];
    const float* Wg = (const float*)d_in[1];
    const float* bg = (const float*)d_in[2];
    const float* W1 = (const float*)d_in[3];
    const float* b1 = (const float*)d_in[4];
    const float* W2 = (const float*)d_in[5];
    const float* b2 = (const float*)d_in[6];
    float* out = (float*)d_out;

    char* ws = (char*)d_ws;
    int*   cnt    = (int*)(ws + 0);
    int*   offs   = (int*)(ws + 64);
    int*   mc     = (int*)(ws + 128);
    int*   g1s    = (int*)(ws + 256);
    int*   g2s    = (int*)(ws + 2304);
    int*   tbl1   = (int*)(ws + 3072);
    int*   tbl2   = (int*)(ws + 14336);
    int*   top_e  = (int*)(ws + 19712);
    int*   rnk    = (int*)(ws + 19712 + 16384);
    float* top_p  = (float*)(ws + 19712 + 2 * 16384);
    int*   perm   = (int*)(ws + 19712 + 3 * 16384);
    float* gate_s = (float*)(ws + 19712 + 4 * 16384);
    unsigned short* Xg   = (unsigned short*)(ws + 101632);
    unsigned short* H    = (unsigned short*)(ws + 101632 + (size_t)N_TOK * DIM * 2);
    float*          part = (float*)(ws + 69307648ull);   // [4][4096][768] f32, 50.3MB
    // total ws: ~119.6 MB (r8 proved ws_size >= 258MB)

    moe_init<<<1, 64, 0, stream>>>(cnt);
    moe_gating<<<N_TOK / 4, 256, 0, stream>>>(x, Wg, bg, cnt, top_e, rnk, top_p);
    moe_scan<<<1, 64, 0, stream>>>(cnt, offs, mc, g1s, g2s);
    moe_fill<<<(G1GRID + G2GRID + 255) / 256, 256, 0, stream>>>(mc, g1s, g2s, tbl1, tbl2);
    moe_mkperm<<<N_TOK / 256, 256, 0, stream>>>(top_e, rnk, top_p, offs, perm, gate_s);
    moe_gather<<<N_TOK, 256, 0, stream>>>(x, perm, Xg);

    moe_gemm<1><<<G1GRID, 256, 0, stream>>>(Xg, W1, b1, cnt, offs, tbl1, H, part);
    moe_gemm<2><<<G2GRID, 256, 0, stream>>>(H, W2, b2, cnt, offs, tbl2, H, part);
    moe_reduce<<<N_TOK, 192, 0, stream>>>(part, perm, gate_s, top_e, b2, out);
}